// Round 1
// baseline (554.010 us; speedup 1.0000x reference)
//
#include <hip/hip_runtime.h>

// Capsule routing: B=32, N_IN=2048, IN_DIM=32, N_OUT=64, OUT_DIM=32, 3 iterations.
#define NI   2048
#define NO   64
#define DD   32
#define ODIM 2048   // NO*DD, the fused (o,d) axis

typedef short bf16x8 __attribute__((ext_vector_type(8)));
typedef float f32x4  __attribute__((ext_vector_type(4)));

__device__ __forceinline__ unsigned short f2bf(float f) {
  unsigned int x = __float_as_uint(f);
  x += 0x7fffu + ((x >> 16) & 1u);   // RNE
  return (unsigned short)(x >> 16);
}
__device__ __forceinline__ float bflo(unsigned int u) { return __uint_as_float(u << 16); }
__device__ __forceinline__ float bfhi(unsigned int u) { return __uint_as_float(u & 0xffff0000u); }

// K1: u_hat[b][i][od] (bf16) = sum_k W[o,i,d,k]*x[b,i,k], via MFMA 16x16x32 bf16.
// Also accumulates per-(i-block) partial sums of u_hat over i (for iter-1 s, c==1/64).
// wave <-> (od-chunk of 64 rows, i-block of 32). 2048 waves = 512 blocks.
__global__ __launch_bounds__(256) void k1_uhat(
    const float* __restrict__ W, const float* __restrict__ X,
    unsigned short* __restrict__ U, float* __restrict__ part) {
  const int tid   = threadIdx.x;
  const int lane  = tid & 63;
  const int wid   = (blockIdx.x << 2) + (tid >> 6);
  const int odc   = wid & 31;    // od-chunk: rows [odc*64, odc*64+64)
  const int ib    = wid >> 5;    // i-block: i in [ib*32, ib*32+32)
  const int row16 = lane & 15;   // A row within 16
  const int kg    = lane >> 4;   // k-group
  const int k0    = kg << 3;     // k offset (8 contiguous)
  const int crow  = kg << 2;     // C/D row base: (lane>>4)*4 + reg   [m89 verified]
  const int ccol  = lane & 15;   // C/D col = lane&15

  f32x4 sacc[4][2];
#pragma unroll
  for (int a = 0; a < 4; ++a)
#pragma unroll
    for (int bt = 0; bt < 2; ++bt) sacc[a][bt] = f32x4{0.f, 0.f, 0.f, 0.f};

  for (int ii = 0; ii < 32; ++ii) {
    const int i = (ib << 5) + ii;
    // B fragments: B[k][b] from x[b,i,k] -> lane (l&15)=b-col reads 8 contiguous k
    bf16x8 bfrag[2];
#pragma unroll
    for (int bt = 0; bt < 2; ++bt) {
      const int bcol = ccol + (bt << 4);
      const float* xp = X + (((size_t)(bcol * NI + i)) << 5) + k0;
      const float4 x0 = *(const float4*)xp;
      const float4 x1 = *(const float4*)(xp + 4);
      bf16x8 t;
      t[0] = (short)f2bf(x0.x); t[1] = (short)f2bf(x0.y);
      t[2] = (short)f2bf(x0.z); t[3] = (short)f2bf(x0.w);
      t[4] = (short)f2bf(x1.x); t[5] = (short)f2bf(x1.y);
      t[6] = (short)f2bf(x1.z); t[7] = (short)f2bf(x1.w);
      bfrag[bt] = t;
    }
#pragma unroll
    for (int a = 0; a < 4; ++a) {
      // od rows R = odc*64 + a*16 .. +16 ; o = R>>5, dbase = R&31
      const int o_a = (odc << 1) + (a >> 1);
      const int db  = (a & 1) << 4;
      const float* wp = W + (((size_t)(o_a * NI + i)) << 10) + ((db + row16) << 5) + k0;
      const float4 w0 = *(const float4*)wp;
      const float4 w1 = *(const float4*)(wp + 4);
      bf16x8 af;
      af[0] = (short)f2bf(w0.x); af[1] = (short)f2bf(w0.y);
      af[2] = (short)f2bf(w0.z); af[3] = (short)f2bf(w0.w);
      af[4] = (short)f2bf(w1.x); af[5] = (short)f2bf(w1.y);
      af[6] = (short)f2bf(w1.z); af[7] = (short)f2bf(w1.w);
#pragma unroll
      for (int bt = 0; bt < 2; ++bt) {
        f32x4 d = __builtin_amdgcn_mfma_f32_16x16x32_bf16(
            af, bfrag[bt], f32x4{0.f, 0.f, 0.f, 0.f}, 0, 0, 0);
        sacc[a][bt] += d;
        const int b  = ccol + (bt << 4);
        const int od = (odc << 6) + (a << 4) + crow;     // 4 consecutive od per lane
        const size_t off = (((size_t)(b * NI + i)) << 11) + od;
        uint2 pk;
        pk.x = (unsigned int)f2bf(d[0]) | ((unsigned int)f2bf(d[1]) << 16);
        pk.y = (unsigned int)f2bf(d[2]) | ((unsigned int)f2bf(d[3]) << 16);
        *(uint2*)(U + off) = pk;   // 8B store, 4 contiguous bf16
      }
    }
  }
  // write per-i-block partial sums: part[ib][b][od]
#pragma unroll
  for (int a = 0; a < 4; ++a)
#pragma unroll
    for (int bt = 0; bt < 2; ++bt) {
      const int b  = ccol + (bt << 4);
      const int od = (odc << 6) + (a << 4) + crow;
      float* pp = part + (((size_t)((ib << 5) + b)) << 11) + od;
      float4 t; t.x = sacc[a][bt][0]; t.y = sacc[a][bt][1];
      t.z = sacc[a][bt][2]; t.w = sacc[a][bt][3];
      *(float4*)pp = t;
    }
}

// Reduce partials over 64 chunks -> s[b,o,:], squash -> vout[b][o][d].
// wave <-> (b,o). 2048 waves = 512 blocks. scale: 1/64 for iter 1 (uniform c), else 1.
__global__ __launch_bounds__(256) void k_reduce(
    const float* __restrict__ part, float* __restrict__ vout, float scale) {
  const int tid  = threadIdx.x;
  const int lane = tid & 63;
  const int wid  = (blockIdx.x << 2) + (tid >> 6);
  const int o = wid & 63, b = wid >> 6;
  const int d = lane & 31, h = lane >> 5;
  float s = 0.f;
  for (int c = h; c < 64; c += 2)
    s += part[(((size_t)((c << 5) + b)) << 11) + (o << 5) + d];
  s += __shfl_xor(s, 32);
  s *= scale;
  float p = s * s;
#pragma unroll
  for (int off = 1; off < 32; off <<= 1) p += __shfl_xor(p, off);
  const float v = (p > 0.f) ? s * sqrtf(p) / (1.f + p) : 0.f;
  if (h == 0) vout[(((b << 6) + o) << 5) + d] = v;
}

// Routing pass: per (b,i): logits[o] = sum_d u*(v1[+v2]); softmax over o (64 lanes);
// partial s accumulation in registers; per-block LDS combine -> part[chunk][b][od].
// block <-> (b, chunk of 32 i); 4 waves x 8 i each. lane <-> o.
__global__ __launch_bounds__(256) void k_route(
    const unsigned short* __restrict__ U, const float* __restrict__ V1,
    const float* __restrict__ V2, float* __restrict__ part) {
  __shared__ float red[4][ODIM];   // 32 KiB
  const int tid   = threadIdx.x;
  const int lane  = tid & 63;
  const int w     = tid >> 6;
  const int b     = blockIdx.x >> 6;
  const int chunk = blockIdx.x & 63;
  const int o     = lane;

  // v (or v1+v2) for this lane's o: 32 regs, reused across all i
  float vs[32];
  {
    const float* vp = V1 + (((b << 6) + o) << 5);
#pragma unroll
    for (int j = 0; j < 8; ++j) {
      const float4 t = *(const float4*)(vp + (j << 2));
      vs[4*j+0] = t.x; vs[4*j+1] = t.y; vs[4*j+2] = t.z; vs[4*j+3] = t.w;
    }
    if (V2 != nullptr) {
      const float* vq = V2 + (((b << 6) + o) << 5);
#pragma unroll
      for (int j = 0; j < 8; ++j) {
        const float4 t = *(const float4*)(vq + (j << 2));
        vs[4*j+0] += t.x; vs[4*j+1] += t.y; vs[4*j+2] += t.z; vs[4*j+3] += t.w;
      }
    }
  }

  float pacc[32];
#pragma unroll
  for (int d = 0; d < 32; ++d) pacc[d] = 0.f;

  const int i0 = (chunk << 5) + (w << 3);
  const unsigned short* ub = U + (((size_t)b * NI) << 11);

  uint4 q0, q1, q2, q3;   // prefetched 64B u-row slice for this lane's o
  {
    const uint4* p = (const uint4*)(ub + (((size_t)i0) << 11) + (o << 5));
    q0 = p[0]; q1 = p[1]; q2 = p[2]; q3 = p[3];
  }
  for (int ii = 0; ii < 8; ++ii) {
    const uint4 c0 = q0, c1 = q1, c2 = q2, c3 = q3;
    if (ii < 7) {
      const uint4* p = (const uint4*)(ub + (((size_t)(i0 + ii + 1)) << 11) + (o << 5));
      q0 = p[0]; q1 = p[1]; q2 = p[2]; q3 = p[3];
    }
    float uf[32];
    uf[ 0]=bflo(c0.x); uf[ 1]=bfhi(c0.x); uf[ 2]=bflo(c0.y); uf[ 3]=bfhi(c0.y);
    uf[ 4]=bflo(c0.z); uf[ 5]=bfhi(c0.z); uf[ 6]=bflo(c0.w); uf[ 7]=bfhi(c0.w);
    uf[ 8]=bflo(c1.x); uf[ 9]=bfhi(c1.x); uf[10]=bflo(c1.y); uf[11]=bfhi(c1.y);
    uf[12]=bflo(c1.z); uf[13]=bfhi(c1.z); uf[14]=bflo(c1.w); uf[15]=bfhi(c1.w);
    uf[16]=bflo(c2.x); uf[17]=bfhi(c2.x); uf[18]=bflo(c2.y); uf[19]=bfhi(c2.y);
    uf[20]=bflo(c2.z); uf[21]=bfhi(c2.z); uf[22]=bflo(c2.w); uf[23]=bfhi(c2.w);
    uf[24]=bflo(c3.x); uf[25]=bfhi(c3.x); uf[26]=bflo(c3.y); uf[27]=bfhi(c3.y);
    uf[28]=bflo(c3.z); uf[29]=bfhi(c3.z); uf[30]=bflo(c3.w); uf[31]=bfhi(c3.w);

    float dotA = 0.f, dotB = 0.f;
#pragma unroll
    for (int d = 0; d < 16; ++d) {
      dotA = fmaf(uf[d], vs[d], dotA);
      dotB = fmaf(uf[d + 16], vs[d + 16], dotB);
    }
    const float dot = dotA + dotB;
    float m = dot;
#pragma unroll
    for (int off = 1; off < 64; off <<= 1) m = fmaxf(m, __shfl_xor(m, off));
    const float e = __expf(dot - m);
    float Z = e;
#pragma unroll
    for (int off = 1; off < 64; off <<= 1) Z += __shfl_xor(Z, off);
    const float c = e / Z;
#pragma unroll
    for (int d = 0; d < 32; ++d) pacc[d] = fmaf(c, uf[d], pacc[d]);
  }

#pragma unroll
  for (int j = 0; j < 8; ++j) {
    float4 t; t.x = pacc[4*j]; t.y = pacc[4*j+1]; t.z = pacc[4*j+2]; t.w = pacc[4*j+3];
    *(float4*)&red[w][(o << 5) + (j << 2)] = t;
  }
  __syncthreads();
  float* pout = part + (((size_t)((chunk << 5) + b)) << 11);
  for (int t = tid; t < ODIM; t += 256)
    pout[t] = red[0][t] + red[1][t] + red[2][t] + red[3][t];
}

extern "C" void kernel_launch(void* const* d_in, const int* in_sizes, int n_in,
                              void* d_out, int out_size, void* d_ws, size_t ws_size,
                              hipStream_t stream) {
  const float* X = (const float*)d_in[0];   // [32][2048][32]
  const float* W = (const float*)d_in[1];   // [64][2048][32][32]
  float* out = (float*)d_out;               // [32][64][32]
  char* ws = (char*)d_ws;

  // ws layout: u_hat bf16 256MiB | part fp32 16MiB | v1 | v2   (~272.5 MiB)
  unsigned short* U = (unsigned short*)ws;
  float* part = (float*)(ws + ((size_t)268435456));
  float* v1   = (float*)(ws + ((size_t)268435456 + 16777216));
  float* v2   = v1 + 65536;

  // iter 1: u_hat + uniform-c partial sums fused
  k1_uhat<<<512, 256, 0, stream>>>(W, X, U, part);
  k_reduce<<<512, 256, 0, stream>>>(part, v1, 1.f / 64.f);
  // iter 2: logits = u.v1
  k_route<<<2048, 256, 0, stream>>>(U, v1, nullptr, part);
  k_reduce<<<512, 256, 0, stream>>>(part, v2, 1.f);
  // iter 3: logits = u.v1 + u.v2 = u.(v1+v2)
  k_route<<<2048, 256, 0, stream>>>(U, v1, v2, part);
  k_reduce<<<512, 256, 0, stream>>>(part, out, 1.f);
}